// Round 9
// baseline (220.452 us; speedup 1.0000x reference)
//
#include <hip/hip_runtime.h>
#include <hip/hip_bf16.h>
#include <stdint.h>

// ---------- types ----------
typedef __attribute__((ext_vector_type(8))) short short8;   // 8 x bf16 (raw)
typedef __attribute__((ext_vector_type(4))) float f32x4;

typedef const __attribute__((address_space(1))) void gv_t;
typedef __attribute__((address_space(3))) void lv_t;

#define SCQ 0.18033688011112042f   // log2(e)/sqrt(64), folded into Q projection

__device__ __forceinline__ void gl_lds16(const void* g, void* l) {
    // async global->LDS, 16B per lane; LDS dest must be waveBase + lane*16
    __builtin_amdgcn_global_load_lds((gv_t*)g, (lv_t*)l, 16, 0, 0);
}

__device__ __forceinline__ unsigned short f2bf(float f) {
    union { float f; unsigned int u; } v; v.f = f;
    unsigned int r = v.u + 0x7fffu + ((v.u >> 16) & 1u);   // RNE
    return (unsigned short)(r >> 16);
}

__device__ __forceinline__ unsigned int pack2bf(float a, float b) {
    union { __hip_bfloat162 h2; unsigned int u; } cv;
    cv.h2 = __float22bfloat162_rn(make_float2(a, b));   // v_cvt_pk_bf16_f32 on gfx950
    return cv.u;                                        // low = a, high = b
}

__device__ __forceinline__ f32x4 zero4() { f32x4 z = {0.f, 0.f, 0.f, 0.f}; return z; }

// ---------- fused prep: LoRA weight fold (Wqkv & Wmsa) + y->bf16 cvt ----------
__global__ void k_prep(const float* __restrict__ y,
                       const float* __restrict__ Wqkv, const float* __restrict__ Wmsa,
                       const float* __restrict__ Bq, const float* __restrict__ Aq,
                       const float* __restrict__ Bk, const float* __restrict__ Ak,
                       const float* __restrict__ Bv, const float* __restrict__ Av,
                       const float* __restrict__ Bo, const float* __restrict__ Ao,
                       unsigned short* __restrict__ wout, unsigned short* __restrict__ yb) {
    const int bid = blockIdx.x;
    if (bid < 16384) {
        int idx = bid * 256 + threadIdx.x;     // n*1024 + k, n in [0,4096)
        int n = idx >> 10, k = idx & 1023;
        int sel = n >> 10, n0 = n & 1023;
        const float* Bp = (sel == 0) ? Bq : (sel == 1) ? Bk : (sel == 2) ? Bv : Bo;
        const float* Ap = (sel == 0) ? Aq : (sel == 1) ? Ak : (sel == 2) ? Av : Ao;
        float acc = (sel < 3) ? Wqkv[idx] : Wmsa[idx - 3145728];
        #pragma unroll
        for (int r = 0; r < 8; ++r) acc += Bp[k * 8 + r] * Ap[r * 1024 + n0];
        wout[idx] = f2bf(acc * ((sel == 0) ? SCQ : 1.0f));
    } else {
        int i = ((bid - 16384) * 256 + threadIdx.x) * 4;
        float4 v = *(const float4*)(y + i);
        union { unsigned short u[4]; uint2 w; } o;
        o.u[0] = f2bf(v.x); o.u[1] = f2bf(v.y); o.u[2] = f2bf(v.z); o.u[3] = f2bf(v.w);
        *(uint2*)(yb + i) = o.w;
    }
}

// ---------- GEMM: C[M,N] = A[M,K](bf16) @ B[N,K]^T(bf16), dbuf cross-barrier prefetch ----------
// EPI=0: bf16(acc+bias[col]); cols<1024 get SCQ on bias; cols>=2048 (V) written transposed
//        into vtg[b,h][d][tok].  EPI=1: fp32(acc + yres).
template <int TM, int EPI, int MINW>
__global__ __launch_bounds__(256, MINW) void k_gemm(const unsigned short* __restrict__ Ag,
                                                    const unsigned short* __restrict__ Bg,
                                                    const float* __restrict__ bias,
                                                    const float* __restrict__ yres,
                                                    unsigned short* __restrict__ vtg,
                                                    void* __restrict__ Cout,
                                                    int M, int N, int K) {
    constexpr int WAVES_N = 256 / TM;
    constexpr int WN = TM / 2;
    constexpr int NI = WN / 16;
    constexpr int ACALLS = TM / 64;
    __shared__ unsigned short As[2][TM * 32];
    __shared__ unsigned short Bs[2][128 * 32];
    const int flat = threadIdx.x;
    const int m0 = blockIdx.y * TM, n0 = blockIdx.x * 128;
    const int lane = flat & 63, wave = flat >> 6;
    const int l16 = lane & 15, quad = lane >> 4;
    const int wm = (wave / WAVES_N) * 64, wn = (wave % WAVES_N) * WN;

    f32x4 acc[4][NI];
    #pragma unroll
    for (int mi = 0; mi < 4; ++mi)
        #pragma unroll
        for (int ni = 0; ni < NI; ++ni) acc[mi][ni] = zero4();

    const unsigned short* ap = Ag + (size_t)(m0 + (flat >> 2)) * K + (flat & 3) * 8;
    const unsigned short* bp = Bg + (size_t)(n0 + (flat >> 2)) * K + (flat & 3) * 8;
    const size_t rstep = (size_t)64 * K;

    #pragma unroll
    for (int c = 0; c < ACALLS; ++c) gl_lds16(ap + c * rstep, &As[0][c * 2048 + flat * 8]);
    gl_lds16(bp,         &Bs[0][flat * 8]);
    gl_lds16(bp + rstep, &Bs[0][2048 + flat * 8]);
    ap += 32; bp += 32;
    __syncthreads();

    for (int k0 = 0; k0 < K; k0 += 32) {
        const int cur = (k0 >> 5) & 1;
        if (k0 + 32 < K) {
            const int nxt = cur ^ 1;
            #pragma unroll
            for (int c = 0; c < ACALLS; ++c) gl_lds16(ap + c * rstep, &As[nxt][c * 2048 + flat * 8]);
            gl_lds16(bp,         &Bs[nxt][flat * 8]);
            gl_lds16(bp + rstep, &Bs[nxt][2048 + flat * 8]);
            ap += 32; bp += 32;
        }

        short8 af[4], bfr[NI];
        #pragma unroll
        for (int i = 0; i < 4; ++i) af[i] = *(const short8*)&As[cur][(wm + i * 16 + l16) * 32 + quad * 8];
        #pragma unroll
        for (int i = 0; i < NI; ++i) bfr[i] = *(const short8*)&Bs[cur][(wn + i * 16 + l16) * 32 + quad * 8];
        #pragma unroll
        for (int mi = 0; mi < 4; ++mi)
            #pragma unroll
            for (int ni = 0; ni < NI; ++ni)
                acc[mi][ni] = __builtin_amdgcn_mfma_f32_16x16x32_bf16(af[mi], bfr[ni], acc[mi][ni], 0, 0, 0);

        __syncthreads();
    }

    // epilogue: C/D layout col=lane&15, row=quad*4+reg
    if (EPI == 0) {
        unsigned short* C = (unsigned short*)Cout;
        if (n0 < 2048) {      // Q/K columns: normal row-major bf16 store
            #pragma unroll
            for (int ni = 0; ni < NI; ++ni) {
                int col = n0 + wn + ni * 16 + l16;
                float bv = bias[col] * ((col < 1024) ? SCQ : 1.0f);
                #pragma unroll
                for (int mi = 0; mi < 4; ++mi) {
                    int row = m0 + wm + mi * 16 + quad * 4;
                    #pragma unroll
                    for (int r = 0; r < 4; ++r)
                        C[(size_t)(row + r) * N + col] = f2bf(acc[mi][ni][r] + bv);
                }
            }
        } else {              // V columns: write transposed into vtg[(b*16+h)*64+d][tok]
            #pragma unroll
            for (int ni = 0; ni < NI; ++ni) {
                int col = n0 + wn + ni * 16 + l16;
                float bv = bias[col];
                int hh = (col - 2048) >> 6, dd = col & 63;
                unsigned short* vrow0 = vtg + (size_t)(hh * 64 + dd) * 2048;
                #pragma unroll
                for (int mi = 0; mi < 4; ++mi) {
                    int row = m0 + wm + mi * 16 + quad * 4;
                    int bb = row >> 11, ss = row & 2047;
                    uint2 w;
                    w.x = pack2bf(acc[mi][ni][0] + bv, acc[mi][ni][1] + bv);
                    w.y = pack2bf(acc[mi][ni][2] + bv, acc[mi][ni][3] + bv);
                    *(uint2*)(vrow0 + (size_t)bb * 2097152 + ss) = w;   // 16*64*2048
                }
            }
        }
    } else {
        float* C = (float*)Cout;
        #pragma unroll
        for (int ni = 0; ni < NI; ++ni) {
            int col = n0 + wn + ni * 16 + l16;
            #pragma unroll
            for (int mi = 0; mi < 4; ++mi) {
                int row = m0 + wm + mi * 16 + quad * 4;
                #pragma unroll
                for (int r = 0; r < 4; ++r)
                    C[(size_t)(row + r) * N + col] = acc[mi][ni][r] + yres[(size_t)(row + r) * N + col];
            }
        }
    }
}

// ---------- fused flash attention, split-K (2 halves), fp32 partial output ----------
// blockIdx.z = b*2 + ks; each block covers K-range [ks*1024, ks*1024+1024) in 16 j-iters.
// Shift-free softmax (Q pre-scaled): partials combine exactly as (O0+O1)/(l0+l1).
__global__ __launch_bounds__(256, 3) void k_attn(const unsigned short* __restrict__ qkv,
                                                 const unsigned short* __restrict__ vtg,
                                                 float* __restrict__ op0,
                                                 float* __restrict__ op1,
                                                 float* __restrict__ lp) {
    __shared__ unsigned short LDS[24576];          // 48 KB
    unsigned short* Qs = LDS;                      // [128][64] swizzled (aliased by Ps)
    unsigned short* Ps = LDS;                      // [128][64] (rows=q, cols=k)
    unsigned short* Ks0 = LDS + 8192;              // [2][64][64]
    unsigned short* Vt0 = LDS + 16384;             // [2][64][64]  (rows=d, cols=k)

    const int t = threadIdx.x;
    const int lane = t & 63, wave = t >> 6;
    const int l16 = lane & 15, quad = lane >> 4;
    const int l8 = l16 & 7;
    const int q0 = blockIdx.x * 128;
    const int h = blockIdx.y;
    const int b = blockIdx.z >> 1, ks = blockIdx.z & 1;
    const int j0 = ks * 16;                        // first K-tile of this half

    const unsigned short* qbase = qkv + (size_t)(b * 2048) * 3072 + h * 64;
    const unsigned short* kbase = qbase + 1024;
    const unsigned short* vtbase = vtg + (size_t)((b * 16 + h) * 64) * 2048;

    // stage Q tile [128][64] swizzled
    #pragma unroll
    for (int i = 0; i < 4; ++i) {
        int B = i * 256 + t;                       // 16B-block index 0..1023
        int row = B >> 3, c = (B & 7) ^ (row & 7);
        gl_lds16(qbase + (size_t)(q0 + row) * 3072 + c * 8, &Qs[B * 8]);
    }

    // per-lane staging constants for K / Vt tiles (512 blocks each)
    const int B0 = t, B1 = t + 256;
    const int r0 = B0 >> 3, c0 = (B0 & 7) ^ (r0 & 7);
    const int r1 = B1 >> 3, c1 = (B1 & 7) ^ (r1 & 7);
    const unsigned short* kp0 = kbase + (size_t)(j0 * 64 + r0) * 3072 + c0 * 8;
    const unsigned short* kp1 = kbase + (size_t)(j0 * 64 + r1) * 3072 + c1 * 8;
    const unsigned short* vp0 = vtbase + (size_t)r0 * 2048 + j0 * 64 + c0 * 8;
    const unsigned short* vp1 = vtbase + (size_t)r1 * 2048 + j0 * 64 + c1 * 8;

    // prefetch tile 0 into buffer 0
    gl_lds16(kp0, &Ks0[B0 * 8]);
    gl_lds16(kp1, &Ks0[B1 * 8]);
    gl_lds16(vp0, &Vt0[B0 * 8]);
    gl_lds16(vp1, &Vt0[B1 * 8]);
    kp0 += 64 * 3072; kp1 += 64 * 3072; vp0 += 64; vp1 += 64;

    __syncthreads();                               // Q + tile0 staged & visible

    // preload Q B-fragments (loop-invariant): B[n=q][k=d], n = wave*32 + ni*16 + l16
    short8 qf[2][2];
    #pragma unroll
    for (int ni = 0; ni < 2; ++ni)
        #pragma unroll
        for (int kk = 0; kk < 2; ++kk)
            qf[ni][kk] = *(const short8*)&Qs[(wave * 32 + ni * 16 + l16) * 64 + ((kk * 4 + quad) ^ l8) * 8];

    __syncthreads();                               // all qf reads done before any Ps write

    f32x4 acc_o[2][4];
    #pragma unroll
    for (int mo = 0; mo < 2; ++mo)
        #pragma unroll
        for (int nd = 0; nd < 4; ++nd) acc_o[mo][nd] = zero4();
    f32x4 acc_l[2] = {zero4(), zero4()};
    short8 ones;
    #pragma unroll
    for (int i = 0; i < 8; ++i) ones[i] = (short)0x3F80;   // bf16 1.0

    for (int j = 0; j < 16; ++j) {
        const unsigned short* Ks = Ks0 + (j & 1) * 4096;
        const unsigned short* Vt = Vt0 + (j & 1) * 4096;

        // prefetch tile j+1 into the other buffer (overlaps this iter's compute)
        if (j < 15) {
            unsigned short* Kn = Ks0 + ((j + 1) & 1) * 4096;
            unsigned short* Vn = Vt0 + ((j + 1) & 1) * 4096;
            gl_lds16(kp0, &Kn[B0 * 8]);
            gl_lds16(kp1, &Kn[B1 * 8]);
            gl_lds16(vp0, &Vn[B0 * 8]);
            gl_lds16(vp1, &Vn[B1 * 8]);
            kp0 += 64 * 3072; kp1 += 64 * 3072; vp0 += 64; vp1 += 64;
        }

        // S^T = K @ Q^T : per wave [64 k x 32 q]
        f32x4 sacc[4][2];
        #pragma unroll
        for (int mi = 0; mi < 4; ++mi)
            #pragma unroll
            for (int ni = 0; ni < 2; ++ni) sacc[mi][ni] = zero4();
        #pragma unroll
        for (int kk = 0; kk < 2; ++kk)
            #pragma unroll
            for (int mi = 0; mi < 4; ++mi) {
                short8 kf = *(const short8*)&Ks[(mi * 16 + l16) * 64 + ((kk * 4 + quad) ^ l8) * 8];
                #pragma unroll
                for (int ni = 0; ni < 2; ++ni)
                    sacc[mi][ni] = __builtin_amdgcn_mfma_f32_16x16x32_bf16(kf, qf[ni][kk], sacc[mi][ni], 0, 0, 0);
            }

        // p = exp2(sacc), pack to bf16, write Ps[q][k]
        #pragma unroll
        for (int ni = 0; ni < 2; ++ni) {
            int qrow = wave * 32 + ni * 16 + l16;
            #pragma unroll
            for (int mi = 0; mi < 4; ++mi) {
                float p0 = __builtin_amdgcn_exp2f(sacc[mi][ni][0]);
                float p1 = __builtin_amdgcn_exp2f(sacc[mi][ni][1]);
                float p2 = __builtin_amdgcn_exp2f(sacc[mi][ni][2]);
                float p3 = __builtin_amdgcn_exp2f(sacc[mi][ni][3]);
                uint2 w; w.x = pack2bf(p0, p1); w.y = pack2bf(p2, p3);
                *(uint2*)&Ps[qrow * 64 + ((2 * mi + (quad >> 1)) ^ l8) * 8 + (quad & 1) * 4] = w;
            }
        }

        // PV + l: O[q][d] += P @ V, l[q] += P @ 1
        #pragma unroll
        for (int kk = 0; kk < 2; ++kk) {
            short8 pf[2];
            #pragma unroll
            for (int mo = 0; mo < 2; ++mo) {
                pf[mo] = *(const short8*)&Ps[(wave * 32 + mo * 16 + l16) * 64 + ((kk * 4 + quad) ^ l8) * 8];
                acc_l[mo] = __builtin_amdgcn_mfma_f32_16x16x32_bf16(pf[mo], ones, acc_l[mo], 0, 0, 0);
            }
            #pragma unroll
            for (int nd = 0; nd < 4; ++nd) {
                short8 vf = *(const short8*)&Vt[(nd * 16 + l16) * 64 + ((kk * 4 + quad) ^ l8) * 8];
                #pragma unroll
                for (int mo = 0; mo < 2; ++mo)
                    acc_o[mo][nd] = __builtin_amdgcn_mfma_f32_16x16x32_bf16(pf[mo], vf, acc_o[mo][nd], 0, 0, 0);
            }
        }

        __syncthreads();   // cur-tile reads done everywhere; drains prefetch
    }

    // epilogue: write fp32 partial O and l (no normalization — done in k_comb)
    float* op = ks ? op1 : op0;
    const size_t hb = ((size_t)(b * 16 + h)) * 2048;
    #pragma unroll
    for (int mo = 0; mo < 2; ++mo)
        #pragma unroll
        for (int rr = 0; rr < 4; ++rr) {
            int qg = q0 + wave * 32 + mo * 16 + quad * 4 + rr;
            float* row = op + (hb + qg) * 64;
            #pragma unroll
            for (int nd = 0; nd < 4; ++nd)
                row[nd * 16 + l16] = acc_o[mo][nd][rr];
            if (l16 == 0)
                lp[(size_t)ks * 65536 + hb + qg] = acc_l[mo][rr];   // 65536 = 32*2048
        }
}

// ---------- combine: o = bf16((O0+O1)/(l0+l1)), [4096 tok][1024] ----------
__global__ __launch_bounds__(256) void k_comb(const float* __restrict__ op0,
                                              const float* __restrict__ op1,
                                              const float* __restrict__ lp,
                                              unsigned short* __restrict__ o) {
    const int tok = blockIdx.x, t = threadIdx.x;
    const int b = tok >> 11, s = tok & 2047, h = t >> 4;
    const size_t hb = ((size_t)(b * 16 + h)) * 2048 + s;
    const size_t base = hb * 64 + (t & 15) * 4;
    float4 O0 = *(const float4*)(op0 + base);
    float4 O1 = *(const float4*)(op1 + base);
    float inv = 1.0f / (lp[hb] + lp[65536 + hb]);
    uint2 w;
    w.x = pack2bf((O0.x + O1.x) * inv, (O0.y + O1.y) * inv);
    w.y = pack2bf((O0.z + O1.z) * inv, (O0.w + O1.w) * inv);
    *(uint2*)(o + (size_t)tok * 1024 + t * 4) = w;
}

// ---------- LayerNorm (row=token, 1024 cols), fp32 in/out ----------
__global__ __launch_bounds__(256) void k_ln(const float* __restrict__ res,
                                            const float* __restrict__ g,
                                            const float* __restrict__ be,
                                            float* __restrict__ out) {
    __shared__ float red[8];
    const int row = blockIdx.x, t = threadIdx.x;
    const float* x = res + (size_t)row * 1024;
    float4 v = *(const float4*)(x + t * 4);
    float s = v.x + v.y + v.z + v.w;
    float sq = v.x * v.x + v.y * v.y + v.z * v.z + v.w * v.w;
    #pragma unroll
    for (int off = 32; off; off >>= 1) { s += __shfl_down(s, off); sq += __shfl_down(sq, off); }
    if ((t & 63) == 0) { red[t >> 6] = s; red[4 + (t >> 6)] = sq; }
    __syncthreads();
    float ts = red[0] + red[1] + red[2] + red[3];
    float tq = red[4] + red[5] + red[6] + red[7];
    float mu = ts * (1.f / 1024.f);
    float var = tq * (1.f / 1024.f) - mu * mu;
    float rstd = rsqrtf(var + 1e-6f);
    float4 gg = *(const float4*)(g + t * 4);
    float4 bb = *(const float4*)(be + t * 4);
    float4 ov;
    ov.x = (v.x - mu) * rstd * gg.x + bb.x;
    ov.y = (v.y - mu) * rstd * gg.y + bb.y;
    ov.z = (v.z - mu) * rstd * gg.z + bb.z;
    ov.w = (v.w - mu) * rstd * gg.w + bb.w;
    *(float4*)(out + (size_t)row * 1024 + t * 4) = ov;
}

// ---------- launch ----------
extern "C" void kernel_launch(void* const* d_in, const int* in_sizes, int n_in,
                              void* d_out, int out_size, void* d_ws, size_t ws_size,
                              hipStream_t stream) {
    (void)in_sizes; (void)n_in; (void)out_size; (void)ws_size;
    const float* y    = (const float*)d_in[0];
    const float* Wqkv = (const float*)d_in[1];
    const float* bqkv = (const float*)d_in[2];
    const float* Wmsa = (const float*)d_in[3];
    const float* Bq = (const float*)d_in[4];
    const float* Aq = (const float*)d_in[5];
    const float* Bk = (const float*)d_in[6];
    const float* Ak = (const float*)d_in[7];
    const float* Bv = (const float*)d_in[8];
    const float* Av = (const float*)d_in[9];
    const float* Bo = (const float*)d_in[10];
    const float* Ao = (const float*)d_in[11];
    const float* gamma = (const float*)d_in[12];
    const float* beta  = (const float*)d_in[13];

    char* ws = (char*)d_ws;
    unsigned short* yb   = (unsigned short*)(ws);               // 8 MB bf16(y); reused as obuf
    unsigned short* weq  = (unsigned short*)(ws + (8u  << 20)); // 6 MB [3072][1024], wem after
    unsigned short* qkv  = (unsigned short*)(ws + (16u << 20)); // 24 MB (Q,K cols used); reused as res
    unsigned short* vtg  = (unsigned short*)(ws + (40u << 20)); // 8 MB [32][64][2048] V^T
    float* op1 = (float*)(ws + (48u << 20));                    // 16 MB attn partial (ks=1)
    float* lp  = (float*)(ws + (64u << 20));                    // 512 KB l partials (both ks)
    unsigned short* wem  = weq + 3145728;                       // 2 MB [1024][1024]
    unsigned short* obuf = yb;
    float* res = (float*)qkv;
    float* op0 = (float*)d_out;                                 // 16 MB scratch until k_ln writes it

    k_prep<<<17408, 256, 0, stream>>>(y, Wqkv, Wmsa, Bq, Aq, Bk, Ak, Bv, Av, Bo, Ao, weq, yb);
    k_gemm<128, 0, 3><<<dim3(24, 32), 256, 0, stream>>>(yb, weq, bqkv, nullptr, vtg, (void*)qkv, 4096, 3072, 1024);
    k_attn<<<dim3(16, 16, 4), 256, 0, stream>>>(qkv, vtg, op0, op1, lp);
    k_comb<<<4096, 256, 0, stream>>>(op0, op1, lp, obuf);
    k_gemm<64, 1, 4><<<dim3(8, 64), 256, 0, stream>>>(obuf, wem, nullptr, y, nullptr, (void*)res, 4096, 1024, 1024);
    k_ln  <<<4096, 256, 0, stream>>>(res, gamma, beta, (float*)d_out);
}